// Round 1
// baseline (184.103 us; speedup 1.0000x reference)
//
#include <hip/hip_runtime.h>

// Problem shape (fixed by reference):
//   feat_s, feat_t : [64, 256, 32, 32] float32, integer values in [0,256)
//   out            : scalar float32
#define NBATCH   64
#define BINS     256
#define PER_BATCH (256 * 32 * 32)          // 262144 elements per batch
#define CHUNKS   16                        // chunks per batch-tensor
#define THREADS  256
#define F4_PER_CHUNK (PER_BATCH / 4 / CHUNKS)     // 4096 float4 per chunk
#define F4_PER_THREAD (F4_PER_CHUNK / THREADS)    // 16 float4 per thread

// ---------------------------------------------------------------------------
// Kernel 1: per-batch histograms for both tensors.
// grid = 128 batch-tensors * 16 chunks = 2048 blocks, 256 threads.
// Per-wave LDS sub-histograms (4 copies) to cut inter-wave LDS atomic
// contention; one global atomicAdd per bin per block to flush.
// ---------------------------------------------------------------------------
__global__ __launch_bounds__(THREADS) void hist_kernel(
    const float* __restrict__ fs, const float* __restrict__ ft,
    int* __restrict__ ghist) {
  __shared__ int sh[4][BINS];
  const int tid = threadIdx.x;

  // zero LDS histograms
  for (int i = tid; i < 4 * BINS; i += THREADS) ((int*)sh)[i] = 0;
  __syncthreads();

  const int tb    = blockIdx.x >> 4;   // 0..127 : batch-tensor index
  const int chunk = blockIdx.x & 15;
  const float* src  = (tb < NBATCH) ? fs : ft;
  const int    batch = tb & (NBATCH - 1);

  const float4* p = (const float4*)(src + (size_t)batch * PER_BATCH)
                    + (size_t)chunk * F4_PER_CHUNK;
  const int w = tid >> 6;  // wave id 0..3

#pragma unroll
  for (int i = 0; i < F4_PER_THREAD; ++i) {
    float4 v = p[(size_t)i * THREADS + tid];  // coalesced 16B/lane
    atomicAdd(&sh[w][((int)v.x) & 255], 1);
    atomicAdd(&sh[w][((int)v.y) & 255], 1);
    atomicAdd(&sh[w][((int)v.z) & 255], 1);
    atomicAdd(&sh[w][((int)v.w) & 255], 1);
  }
  __syncthreads();

  // 256 threads == 256 bins
  int total = sh[0][tid] + sh[1][tid] + sh[2][tid] + sh[3][tid];
  if (total) atomicAdd(&ghist[tb * BINS + tid], total);
}

// ---------------------------------------------------------------------------
// Kernel 2: KL over the 2*64*256 histogram. One block, 16 waves; each wave
// owns 4 batches (64 lanes x 4 bins/lane). fp64 throughout: the result is a
// ~1e-3 sum of cancelling terms, fp64 makes us match the numpy ref exactly.
// ---------------------------------------------------------------------------
__global__ __launch_bounds__(1024) void kl_kernel(
    const int* __restrict__ ghist, float* __restrict__ out) {
  __shared__ double wacc[16];
  const int tid  = threadIdx.x;
  const int wave = tid >> 6;
  const int lane = tid & 63;

  double acc = 0.0;
  for (int n = wave; n < NBATCH; n += 16) {
    const int* hs = ghist + n * BINS;
    const int* ht = ghist + (NBATCH + n) * BINS;

    double ls[4], lt[4];
#pragma unroll
    for (int j = 0; j < 4; ++j) {
      const int bin = lane + 64 * j;
      // prob = log(hist + 1e-8); logits = prob / T, T = 4
      ls[j] = log((double)hs[bin] + 1e-8) * 0.25;
      lt[j] = log((double)ht[bin] + 1e-8) * 0.25;
    }

    double ms = ls[0], mt = lt[0];
#pragma unroll
    for (int j = 1; j < 4; ++j) { ms = fmax(ms, ls[j]); mt = fmax(mt, lt[j]); }
    for (int off = 32; off; off >>= 1) {
      ms = fmax(ms, __shfl_xor(ms, off));
      mt = fmax(mt, __shfl_xor(mt, off));
    }

    double ss = 0.0, st = 0.0;
#pragma unroll
    for (int j = 0; j < 4; ++j) { ss += exp(ls[j] - ms); st += exp(lt[j] - mt); }
    for (int off = 32; off; off >>= 1) {
      ss += __shfl_xor(ss, off);
      st += __shfl_xor(st, off);
    }
    const double lse_s = ms + log(ss);
    const double lse_t = mt + log(st);

    double term = 0.0;
#pragma unroll
    for (int j = 0; j < 4; ++j) {
      const double lpt = lt[j] - lse_t;   // log p_t
      const double lps = ls[j] - lse_s;   // log p_s (log_softmax)
      term += exp(lpt) * (lpt - lps);     // p_t * (log p_t - log p_s)
    }
    for (int off = 32; off; off >>= 1) term += __shfl_xor(term, off);

    if (lane == 0) acc += term;
  }

  if (lane == 0) wacc[wave] = acc;
  __syncthreads();
  if (tid == 0) {
    double t = 0.0;
    for (int i = 0; i < 16; ++i) t += wacc[i];
    out[0] = (float)(t * 0.25);  // * T^2 / N = 16 / 64
  }
}

// ---------------------------------------------------------------------------
extern "C" void kernel_launch(void* const* d_in, const int* in_sizes, int n_in,
                              void* d_out, int out_size, void* d_ws, size_t ws_size,
                              hipStream_t stream) {
  const float* fs = (const float*)d_in[0];
  const float* ft = (const float*)d_in[1];
  int* ghist = (int*)d_ws;  // 2 * 64 * 256 ints = 128 KiB

  // ws is poisoned to 0xAA before every call — zero the histogram region.
  hipMemsetAsync(d_ws, 0, (size_t)2 * NBATCH * BINS * sizeof(int), stream);

  hist_kernel<<<dim3(128 * CHUNKS), dim3(THREADS), 0, stream>>>(fs, ft, ghist);
  kl_kernel<<<dim3(1), dim3(1024), 0, stream>>>(ghist, (float*)d_out);
}

// Round 2
// 169.593 us; speedup vs baseline: 1.0856x; 1.0856x over previous
//
#include <hip/hip_runtime.h>

// Problem shape (fixed by reference):
//   feat_s, feat_t : [64, 256, 32, 32] float32, integer values in [0,256)
//   out            : scalar float32
#define NBATCH    64
#define BINS      256
#define PER_BATCH (256 * 32 * 32)   // 262144 elements per batch
#define THREADS   256
#define CHUNKS    8                 // blocks per batch-tensor
#define F4_PER_THREAD 32            // 128 elements/thread (byte counters stay < 255)
#define F4_PER_CHUNK  (F4_PER_THREAD * THREADS)  // 8192 float4 = 32768 elems/block

// ---------------------------------------------------------------------------
// Kernel 1: per-batch histograms, fully privatized per-THREAD counters.
// LDS layout: sh[group][tid], group = bin>>2; each 32-bit word packs 4 byte
// counters (bins 4g..4g+3) for ONE thread. Updates are ds_add_u32 to the
// thread's own column: bank = tid%32 -> 2 lanes/bank (free), zero same-address
// collisions, no read-dependency (fire-and-forget atomic).
// grid = 128 batch-tensors * 8 chunks = 1024 blocks.
// ---------------------------------------------------------------------------
__global__ __launch_bounds__(THREADS) void hist_kernel(
    const float* __restrict__ fs, const float* __restrict__ ft,
    int* __restrict__ ghist) {
  __shared__ unsigned sh[64 * THREADS];  // 64 KiB
  const int tid = threadIdx.x;

  // Zero own column (thread-private -> no barrier needed before main loop).
#pragma unroll
  for (int g = 0; g < 64; ++g) sh[g * THREADS + tid] = 0u;

  const int tb    = blockIdx.x >> 3;   // 0..127 : batch-tensor index
  const int chunk = blockIdx.x & 7;
  const float* src   = (tb < NBATCH) ? fs : ft;
  const int    batch = tb & (NBATCH - 1);
  const float4* p = (const float4*)(src + (size_t)batch * PER_BATCH)
                    + (size_t)chunk * F4_PER_CHUNK;

#pragma unroll 8
  for (int i = 0; i < F4_PER_THREAD; ++i) {
    float4 v = p[i * THREADS + tid];   // coalesced 16 B/lane
    int b0 = (int)v.x, b1 = (int)v.y, b2 = (int)v.z, b3 = (int)v.w;
    atomicAdd(&sh[((b0 >> 2) << 8) + tid], 1u << ((b0 & 3) << 3));
    atomicAdd(&sh[((b1 >> 2) << 8) + tid], 1u << ((b1 & 3) << 3));
    atomicAdd(&sh[((b2 >> 2) << 8) + tid], 1u << ((b2 & 3) << 3));
    atomicAdd(&sh[((b3 >> 2) << 8) + tid], 1u << ((b3 & 3) << 3));
  }
  __syncthreads();

  // Flush: thread t totals bin b = t. It owns group g = t>>2, quarter t&3 of
  // the 256 columns; masked 16-bit field accumulation (64 * 255 < 65536).
  // Rotated index keeps banks at 2 lanes/bank (free).
  const int g = tid >> 2;
  const unsigned qbase = (unsigned)g * THREADS + (unsigned)(tid & 3) * 64u;
  unsigned acc0 = 0, acc1 = 0;
#pragma unroll 4
  for (int j = 0; j < 64; ++j) {
    unsigned w = sh[qbase + ((j + tid) & 63)];
    acc0 += w & 0x00FF00FFu;          // bytes 0,2 -> bins 4g, 4g+2
    acc1 += (w >> 8) & 0x00FF00FFu;   // bytes 1,3 -> bins 4g+1, 4g+3
  }
  // Combine the 4 quarter-partials (lanes t, t^1, t^2 within the quad).
  acc0 += __shfl_xor(acc0, 1);  acc0 += __shfl_xor(acc0, 2);
  acc1 += __shfl_xor(acc1, 1);  acc1 += __shfl_xor(acc1, 2);

  const int sub = tid & 3;              // which bin of the group this lane flushes
  unsigned cnt = (((sub & 1) ? acc1 : acc0) >> ((sub & 2) * 8)) & 0xFFFFu;
  atomicAdd(&ghist[tb * BINS + tid], (int)cnt);
}

// ---------------------------------------------------------------------------
// Kernel 2: per-batch KL partial, one block per batch (64 blocks x 256 thr).
// fp64 throughout: result is a ~1e-3 sum of cancelling terms (threshold
// 1.9e-5) and this stage is tiny once parallelized across CUs.
// ---------------------------------------------------------------------------
__global__ __launch_bounds__(256) void kl_batch(
    const int* __restrict__ ghist, double* __restrict__ partial) {
  __shared__ double reda[4], redb[4];
  const int n = blockIdx.x, tid = threadIdx.x;
  const int w = tid >> 6, lane = tid & 63;
  const int* hs = ghist + n * BINS;
  const int* ht = ghist + (NBATCH + n) * BINS;

  // logits = log(hist + 1e-8) / T, T = 4
  double ls = log((double)hs[tid] + 1e-8) * 0.25;
  double lt = log((double)ht[tid] + 1e-8) * 0.25;

  // block max (wave shuffle + LDS across 4 waves)
  double ms = ls, mt = lt;
  for (int off = 32; off; off >>= 1) {
    ms = fmax(ms, __shfl_xor(ms, off));
    mt = fmax(mt, __shfl_xor(mt, off));
  }
  if (lane == 0) { reda[w] = ms; redb[w] = mt; }
  __syncthreads();
  ms = fmax(fmax(reda[0], reda[1]), fmax(reda[2], reda[3]));
  mt = fmax(fmax(redb[0], redb[1]), fmax(redb[2], redb[3]));
  __syncthreads();

  // block sum of exp(logit - max)
  double ss = exp(ls - ms), st = exp(lt - mt);
  for (int off = 32; off; off >>= 1) {
    ss += __shfl_xor(ss, off);
    st += __shfl_xor(st, off);
  }
  if (lane == 0) { reda[w] = ss; redb[w] = st; }
  __syncthreads();
  ss = reda[0] + reda[1] + reda[2] + reda[3];
  st = redb[0] + redb[1] + redb[2] + redb[3];
  const double lse_s = ms + log(ss);
  const double lse_t = mt + log(st);

  // KL term: p_t * (log p_t - log p_s)
  const double lpt = lt - lse_t;
  const double lps = ls - lse_s;
  double term = exp(lpt) * (lpt - lps);
  for (int off = 32; off; off >>= 1) term += __shfl_xor(term, off);
  __syncthreads();
  if (lane == 0) reda[w] = term;
  __syncthreads();
  if (tid == 0) partial[n] = reda[0] + reda[1] + reda[2] + reda[3];
}

// ---------------------------------------------------------------------------
// Kernel 3: sum 64 batch partials, scale by T^2/N = 16/64.
// ---------------------------------------------------------------------------
__global__ __launch_bounds__(64) void finalize(
    const double* __restrict__ partial, float* __restrict__ out) {
  double v = partial[threadIdx.x];
  for (int off = 32; off; off >>= 1) v += __shfl_xor(v, off);
  if (threadIdx.x == 0) out[0] = (float)(v * 0.25);
}

// ---------------------------------------------------------------------------
extern "C" void kernel_launch(void* const* d_in, const int* in_sizes, int n_in,
                              void* d_out, int out_size, void* d_ws, size_t ws_size,
                              hipStream_t stream) {
  const float* fs = (const float*)d_in[0];
  const float* ft = (const float*)d_in[1];
  int*    ghist   = (int*)d_ws;                            // 128 KiB
  double* partial = (double*)((char*)d_ws + 2 * NBATCH * BINS * sizeof(int));

  // ws is poisoned to 0xAA before every call — zero the histogram region.
  hipMemsetAsync(d_ws, 0, (size_t)2 * NBATCH * BINS * sizeof(int), stream);

  hist_kernel<<<dim3(128 * CHUNKS), dim3(THREADS), 0, stream>>>(fs, ft, ghist);
  kl_batch<<<dim3(NBATCH), dim3(256), 0, stream>>>(ghist, partial);
  finalize<<<dim3(1), dim3(64), 0, stream>>>(partial, (float*)d_out);
}

// Round 3
// 152.845 us; speedup vs baseline: 1.2045x; 1.1096x over previous
//
#include <hip/hip_runtime.h>

// Problem shape (fixed by reference):
//   feat_s, feat_t : [64, 256, 32, 32] float32, integer values in [0,256)
//   out            : scalar float32
#define NBATCH    64
#define BINS      256
#define PER_BATCH (256 * 32 * 32)   // 262144 elements per batch
#define THREADS   512
#define CHUNKS    8                 // blocks per batch-tensor
#define F4_PER_CHUNK (PER_BATCH / 4 / CHUNKS)  // 8192 float4 per block
// per thread: 16 float4 = 64 elements -> pair-shared byte counter <= 128. Safe.

// ---------------------------------------------------------------------------
// Kernel 1: per-batch histograms. LDS: 64 groups x 256 columns of 32-bit
// words, each word packs 4 byte-counters (bins 4g..4g+3) for one PAIR of
// threads (col = tid>>1). Bank = lane>>1 -> 2 lanes/bank (free, m136).
// Same-address 2-way atomic collision only when a lane pair hits the same
// group (~1/64 of ops). Explicit 4-deep float4 prefetch forces MLP (v1's
// VGPR_Count=8 showed the compiler otherwise serializes to 1 outstanding
// load). 512 thr x 64 KiB -> 2 blocks/CU = 16 waves/CU (~50% occ).
// ---------------------------------------------------------------------------
__global__ __launch_bounds__(THREADS, 4) void hist_kernel(
    const float* __restrict__ fs, const float* __restrict__ ft,
    int* __restrict__ ghist) {
  __shared__ unsigned sh[64 * 256];  // 64 KiB
  const int tid = threadIdx.x;

  // zero LDS (uint4 stores: 16384 words / 512 thr = 32 words = 8 x b128)
  uint4* shv = (uint4*)sh;
#pragma unroll
  for (int k = 0; k < 8; ++k) shv[k * THREADS + tid] = make_uint4(0, 0, 0, 0);
  __syncthreads();

  const int tb    = blockIdx.x >> 3;   // 0..127 : batch-tensor index
  const int chunk = blockIdx.x & 7;
  const float* src   = (tb < NBATCH) ? fs : ft;
  const int    batch = tb & (NBATCH - 1);
  const float4* p = (const float4*)(src + (size_t)batch * PER_BATCH)
                    + (size_t)chunk * F4_PER_CHUNK;

  const unsigned colb = ((unsigned)tid >> 1) << 2;  // column byte offset

#define PROC1(x) {                                        \
    int b = (int)(x);                                     \
    unsigned a = ((unsigned)(b >> 2) << 10) + colb;       \
    atomicAdd((unsigned*)((char*)sh + a),                 \
              1u << ((b & 3) << 3)); }
#define PROC4(v) { PROC1(v.x) PROC1(v.y) PROC1(v.z) PROC1(v.w) }

  // 4-deep prefetch pipeline over 16 float4 per thread
  float4 c0 = p[tid], c1 = p[tid + 512], c2 = p[tid + 1024], c3 = p[tid + 1536];
#pragma unroll
  for (int g = 1; g < 4; ++g) {
    float4 n0 = p[g * 2048 + tid],        n1 = p[g * 2048 + 512 + tid],
           n2 = p[g * 2048 + 1024 + tid], n3 = p[g * 2048 + 1536 + tid];
    PROC4(c0) PROC4(c1) PROC4(c2) PROC4(c3)
    c0 = n0; c1 = n1; c2 = n2; c3 = n3;
  }
  PROC4(c0) PROC4(c1) PROC4(c2) PROC4(c3)
  __syncthreads();

  // Flush (first 256 threads): thread t owns group g=t>>2, quarter q=t&3 of
  // the 256 columns (64 words), masked 16-bit field accumulation. Per-bin
  // block total <= 32768 < 65536 -> provably no field carry. Rotation
  // (j+t)&63 keeps banks at 2 lanes/bank.
  if (tid < 256) {
    const int g = tid >> 2;
    const unsigned qbase = (unsigned)g * 256u + (unsigned)(tid & 3) * 64u;
    unsigned acc0 = 0, acc1 = 0;
#pragma unroll 4
    for (int j = 0; j < 64; ++j) {
      unsigned w = sh[qbase + ((j + tid) & 63)];
      acc0 += w & 0x00FF00FFu;          // bytes 0,2 -> bins 4g, 4g+2
      acc1 += (w >> 8) & 0x00FF00FFu;   // bytes 1,3 -> bins 4g+1, 4g+3
    }
    acc0 += __shfl_xor(acc0, 1);  acc0 += __shfl_xor(acc0, 2);
    acc1 += __shfl_xor(acc1, 1);  acc1 += __shfl_xor(acc1, 2);

    const int sub = tid & 3;
    unsigned cnt = (((sub & 1) ? acc1 : acc0) >> ((sub & 2) * 8)) & 0xFFFFu;
    atomicAdd(&ghist[tb * BINS + tid], (int)cnt);
  }
}

// ---------------------------------------------------------------------------
// Kernel 2: per-batch KL partial, one block per batch (64 blocks x 256 thr).
// fp64: result is a ~1e-3 sum of cancelling terms (threshold 1.9e-5).
// ---------------------------------------------------------------------------
__global__ __launch_bounds__(256) void kl_batch(
    const int* __restrict__ ghist, double* __restrict__ partial) {
  __shared__ double reda[4], redb[4];
  const int n = blockIdx.x, tid = threadIdx.x;
  const int w = tid >> 6, lane = tid & 63;
  const int* hs = ghist + n * BINS;
  const int* ht = ghist + (NBATCH + n) * BINS;

  // logits = log(hist + 1e-8) / T, T = 4
  double ls = log((double)hs[tid] + 1e-8) * 0.25;
  double lt = log((double)ht[tid] + 1e-8) * 0.25;

  double ms = ls, mt = lt;
  for (int off = 32; off; off >>= 1) {
    ms = fmax(ms, __shfl_xor(ms, off));
    mt = fmax(mt, __shfl_xor(mt, off));
  }
  if (lane == 0) { reda[w] = ms; redb[w] = mt; }
  __syncthreads();
  ms = fmax(fmax(reda[0], reda[1]), fmax(reda[2], reda[3]));
  mt = fmax(fmax(redb[0], redb[1]), fmax(redb[2], redb[3]));
  __syncthreads();

  double ss = exp(ls - ms), st = exp(lt - mt);
  for (int off = 32; off; off >>= 1) {
    ss += __shfl_xor(ss, off);
    st += __shfl_xor(st, off);
  }
  if (lane == 0) { reda[w] = ss; redb[w] = st; }
  __syncthreads();
  ss = reda[0] + reda[1] + reda[2] + reda[3];
  st = redb[0] + redb[1] + redb[2] + redb[3];
  const double lse_s = ms + log(ss);
  const double lse_t = mt + log(st);

  const double lpt = lt - lse_t;
  const double lps = ls - lse_s;
  double term = exp(lpt) * (lpt - lps);
  for (int off = 32; off; off >>= 1) term += __shfl_xor(term, off);
  __syncthreads();
  if (lane == 0) reda[w] = term;
  __syncthreads();
  if (tid == 0) partial[n] = reda[0] + reda[1] + reda[2] + reda[3];
}

// ---------------------------------------------------------------------------
// Kernel 3: sum 64 batch partials, scale by T^2/N = 16/64.
// ---------------------------------------------------------------------------
__global__ __launch_bounds__(64) void finalize(
    const double* __restrict__ partial, float* __restrict__ out) {
  double v = partial[threadIdx.x];
  for (int off = 32; off; off >>= 1) v += __shfl_xor(v, off);
  if (threadIdx.x == 0) out[0] = (float)(v * 0.25);
}

// ---------------------------------------------------------------------------
extern "C" void kernel_launch(void* const* d_in, const int* in_sizes, int n_in,
                              void* d_out, int out_size, void* d_ws, size_t ws_size,
                              hipStream_t stream) {
  const float* fs = (const float*)d_in[0];
  const float* ft = (const float*)d_in[1];
  int*    ghist   = (int*)d_ws;                            // 128 KiB
  double* partial = (double*)((char*)d_ws + 2 * NBATCH * BINS * sizeof(int));

  // ws is poisoned to 0xAA before every call — zero the histogram region.
  hipMemsetAsync(d_ws, 0, (size_t)2 * NBATCH * BINS * sizeof(int), stream);

  hist_kernel<<<dim3(128 * CHUNKS), dim3(THREADS), 0, stream>>>(fs, ft, ghist);
  kl_batch<<<dim3(NBATCH), dim3(256), 0, stream>>>(ghist, partial);
  finalize<<<dim3(1), dim3(64), 0, stream>>>(partial, (float*)d_out);
}

// Round 4
// 151.324 us; speedup vs baseline: 1.2166x; 1.0101x over previous
//
#include <hip/hip_runtime.h>

// Problem shape (fixed by reference):
//   feat_s, feat_t : [64, 256, 32, 32] float32, integer values in [0,256)
//   out            : scalar float32
#define NBATCH    64
#define BINS      256
#define PER_BATCH (256 * 32 * 32)   // 262144 elements per batch
#define THREADS   256
#define CHUNKS    16                // blocks per batch-tensor
#define F4_PER_CHUNK (PER_BATCH / 4 / CHUNKS)   // 4096 float4 per block
#define F4_PER_THREAD (F4_PER_CHUNK / THREADS)  // 16 float4 = 64 elems/thread

// ---------------------------------------------------------------------------
// Kernel 1: per-batch histograms. LDS: 64 groups x 128 columns of 32-bit
// words; each word packs 4 byte-counters (bins 4g..4g+3) for one PAIR of
// threads (col = tid>>1). Bank = (tid>>1)%32 (128 cols == 0 mod 32) -> 2
// lanes/bank = free (m136). Pair same-address collisions ~1/64 of ops
// (measured ~3% at R3 — acceptable). Byte counter max = 2 thr x 64 elem =
// 128 <= 255, provably no overflow.
// 32 KiB LDS x 5 blocks = 160 KiB -> 5 blocks/CU, 20 waves/CU (62% occ),
// vs R3's 2 blocks/CU. 8-deep float4 prefetch for MLP.
// Each block WRITES its own 256-bin slab (no global atomics, no memset).
// grid = 128 batch-tensors * 16 chunks = 2048 blocks.
// ---------------------------------------------------------------------------
__global__ __launch_bounds__(THREADS, 5) void hist_kernel(
    const float* __restrict__ fs, const float* __restrict__ ft,
    int* __restrict__ phist) {
  __shared__ unsigned sh[64 * 128];  // 32 KiB
  const int tid = threadIdx.x;

  // zero LDS: 8192 words / 256 thr = 32 words = 8 x uint4 per thread
  uint4* shv = (uint4*)sh;
#pragma unroll
  for (int k = 0; k < 8; ++k) shv[k * THREADS + tid] = make_uint4(0, 0, 0, 0);
  __syncthreads();

  const int tb    = blockIdx.x >> 4;   // 0..127 : batch-tensor index
  const int chunk = blockIdx.x & 15;
  const float* src   = (tb < NBATCH) ? fs : ft;
  const int    batch = tb & (NBATCH - 1);
  const float4* p = (const float4*)(src + (size_t)batch * PER_BATCH)
                    + (size_t)chunk * F4_PER_CHUNK;

  const unsigned colb = ((unsigned)tid >> 1) << 2;  // column byte offset

#define PROC1(x) {                                        \
    int b = (int)(x);                                     \
    unsigned a = ((unsigned)(b >> 2) << 9) + colb;        \
    atomicAdd((unsigned*)((char*)sh + a),                 \
              1u << ((b & 3) << 3)); }
#define PROC4(v) { PROC1(v.x) PROC1(v.y) PROC1(v.z) PROC1(v.w) }

  // 8-deep prefetch pipeline over 16 float4 per thread
  float4 c[8];
#pragma unroll
  for (int k = 0; k < 8; ++k) c[k] = p[k * THREADS + tid];
#pragma unroll
  for (int k = 0; k < 8; ++k) {
    float4 n = p[(8 + k) * THREADS + tid];
    PROC4(c[k])
    c[k] = n;
  }
#pragma unroll
  for (int k = 0; k < 8; ++k) PROC4(c[k])
  __syncthreads();

  // Flush: thread t totals bin b = t. Group g = t>>2, quarter q = t&3 of the
  // 128 columns (32 words each); masked 16-bit field accumulation
  // (32 * 255 = 8160 < 65536 -> no field carry). Rotation (j+t)&31 keeps
  // banks at 2 lanes/bank.
  const int g = tid >> 2;
  const unsigned qbase = (unsigned)g * 128u + (unsigned)(tid & 3) * 32u;
  unsigned acc0 = 0, acc1 = 0;
#pragma unroll 4
  for (int j = 0; j < 32; ++j) {
    unsigned w = sh[qbase + ((j + tid) & 31)];
    acc0 += w & 0x00FF00FFu;          // bytes 0,2 -> bins 4g, 4g+2
    acc1 += (w >> 8) & 0x00FF00FFu;   // bytes 1,3 -> bins 4g+1, 4g+3
  }
  acc0 += __shfl_xor(acc0, 1);  acc0 += __shfl_xor(acc0, 2);
  acc1 += __shfl_xor(acc1, 1);  acc1 += __shfl_xor(acc1, 2);

  const int sub = tid & 3;
  unsigned cnt = (((sub & 1) ? acc1 : acc0) >> ((sub & 2) * 8)) & 0xFFFFu;
  phist[blockIdx.x * BINS + tid] = (int)cnt;   // private slab: plain store
}

// ---------------------------------------------------------------------------
// Kernel 2: per-batch KL partial, one block per batch (64 blocks x 256 thr).
// Sums the 16 chunk-histograms per tensor inline (coalesced), then fp64
// softmax/KL: result is a ~1e-3 sum of cancelling terms (threshold 1.9e-5).
// ---------------------------------------------------------------------------
__global__ __launch_bounds__(256) void kl_batch(
    const int* __restrict__ phist, double* __restrict__ partial) {
  __shared__ double reda[4], redb[4];
  const int n = blockIdx.x, tid = threadIdx.x;
  const int w = tid >> 6, lane = tid & 63;

  int hs = 0, ht = 0;
#pragma unroll
  for (int c = 0; c < CHUNKS; ++c) {
    hs += phist[(n * CHUNKS + c) * BINS + tid];
    ht += phist[((NBATCH + n) * CHUNKS + c) * BINS + tid];
  }

  // logits = log(hist + 1e-8) / T, T = 4
  double ls = log((double)hs + 1e-8) * 0.25;
  double lt = log((double)ht + 1e-8) * 0.25;

  double ms = ls, mt = lt;
  for (int off = 32; off; off >>= 1) {
    ms = fmax(ms, __shfl_xor(ms, off));
    mt = fmax(mt, __shfl_xor(mt, off));
  }
  if (lane == 0) { reda[w] = ms; redb[w] = mt; }
  __syncthreads();
  ms = fmax(fmax(reda[0], reda[1]), fmax(reda[2], reda[3]));
  mt = fmax(fmax(redb[0], redb[1]), fmax(redb[2], redb[3]));
  __syncthreads();

  double ss = exp(ls - ms), st = exp(lt - mt);
  for (int off = 32; off; off >>= 1) {
    ss += __shfl_xor(ss, off);
    st += __shfl_xor(st, off);
  }
  if (lane == 0) { reda[w] = ss; redb[w] = st; }
  __syncthreads();
  ss = reda[0] + reda[1] + reda[2] + reda[3];
  st = redb[0] + redb[1] + redb[2] + redb[3];
  const double lse_s = ms + log(ss);
  const double lse_t = mt + log(st);

  const double lpt = lt - lse_t;
  const double lps = ls - lse_s;
  double term = exp(lpt) * (lpt - lps);
  for (int off = 32; off; off >>= 1) term += __shfl_xor(term, off);
  __syncthreads();
  if (lane == 0) reda[w] = term;
  __syncthreads();
  if (tid == 0) partial[n] = reda[0] + reda[1] + reda[2] + reda[3];
}

// ---------------------------------------------------------------------------
// Kernel 3: sum 64 batch partials, scale by T^2/N = 16/64.
// ---------------------------------------------------------------------------
__global__ __launch_bounds__(64) void finalize(
    const double* __restrict__ partial, float* __restrict__ out) {
  double v = partial[threadIdx.x];
  for (int off = 32; off; off >>= 1) v += __shfl_xor(v, off);
  if (threadIdx.x == 0) out[0] = (float)(v * 0.25);
}

// ---------------------------------------------------------------------------
extern "C" void kernel_launch(void* const* d_in, const int* in_sizes, int n_in,
                              void* d_out, int out_size, void* d_ws, size_t ws_size,
                              hipStream_t stream) {
  const float* fs = (const float*)d_in[0];
  const float* ft = (const float*)d_in[1];
  // ws: 2048 block-private 256-bin histograms (2 MiB) + 64 doubles.
  int*    phist   = (int*)d_ws;
  double* partial = (double*)((char*)d_ws + (size_t)128 * CHUNKS * BINS * sizeof(int));

  hist_kernel<<<dim3(128 * CHUNKS), dim3(THREADS), 0, stream>>>(fs, ft, phist);
  kl_batch<<<dim3(NBATCH), dim3(256), 0, stream>>>(phist, partial);
  finalize<<<dim3(1), dim3(64), 0, stream>>>(partial, (float*)d_out);
}